// Round 2
// baseline (327.888 us; speedup 1.0000x reference)
//
// ============================================================================
// Round 15: (1) spmm: per-(bucket,g) blocks (grid 782x3), EDGE-BALANCED group
// windows (binary-search node bounds in rs, run-walk, partial sums combined in
// 16KB LDS agg via LDS atomicAdd, relu once after barrier, fp32 atomicAdd into
// out). Fixes serial-g barriers + max-of-8-Poisson wave inflation (~1.37x).
// (2) scan_off kernel DELETED: partition & sort redundantly recompute the
// 98-bin scan from tot in LDS; cursor is zero-based. (3) partition + gemm
// fused into one block-specialized pg_kernel (partition blocks first).
// (4) out zeroed inside prep's conv branch (spmm accumulates atomically).
// Pipeline: memset, prep, pg, sort, spmm = 5 dispatches (was 7).
//
// Measured R14: 268.7 us. spmm 69.3 (29% HBM, Occ 39%, VALU 31%) - latency/
// balance-bound. absmax 0.001953125 bit-identical (W-perm epilogue verified).
//
// Predicted: spmm -> ~45 (Occ >60%, FETCH +13MB out-RMW), pg ~30-40 replacing
// ~55-60 of serial gemm+partition+scan, prep +2-3. Total -> ~225-240.
// absmax ~0.00195 (+-1ulp from atomic ordering). If spmm > 55: run-walk
// divergence/flush overhead ate the balance win -> revert to node-per-group.
// ============================================================================
#include <hip/hip_runtime.h>

#define KDIM 128
#define NCOLS 64
// u8-packed src-degree histogram: one range, 50000 bins / 4 per word
#define NHCH 64
#define HW 12500
// coarse buckets
#define COARSE 512
#define NC 98
#define SFCAP 17408
// fine buckets (spmm granularity)
#define BUCKET 64
#define NBUCK 782
#define FCAP 2816
// partition blocks per graph
#define NPB 85
// prep task ranges
#define PREP_HIST (3 * NHCH)   // 192 hist blocks
#define PREP_CNT  (3 * NPB)    // 255 coarse-count blocks
#define PREP_WF   12           // wfrag blocks
#define PREP_CONV 565          // convert + out-zero blocks (grid-stride)
#define PREP_GRID (PREP_HIST + PREP_CNT + PREP_WF + PREP_CONV)  // 1024
// pg (partition + gemm fused) ranges: partition FIRST (long-pole scatter)
#define PG_PART (3 * NPB)            // 255
#define PG_GEMM_PER 391              // (50000+127)/128
#define PG_GEMM (3 * PG_GEMM_PER)    // 1173
#define PG_GRID (PG_PART + PG_GEMM)  // 1428

typedef __attribute__((ext_vector_type(8))) short bf16x8;
typedef __attribute__((ext_vector_type(4))) float f32x4;

struct GArgs {
  const int*   src[3];
  const int*   dst[3];
  const float* W[3];
  const float* b[3];
  int          E[3];
};

__device__ __forceinline__ unsigned short f2bf(float f) {
  unsigned u = __float_as_uint(f);
  u += 0x7FFFu + ((u >> 16) & 1u);   // RNE
  return (unsigned short)(u >> 16);
}
__device__ __forceinline__ float bflo(unsigned u) { return __uint_as_float(u << 16); }
__device__ __forceinline__ float bfhi(unsigned u) { return __uint_as_float(u & 0xFFFF0000u); }

// ---------------- fused front-end: hist | count | wfrag | convert+zero ------
__global__ __launch_bounds__(256) void prep_kernel(
    GArgs A, const float* __restrict__ h, unsigned short* __restrict__ hb,
    unsigned short* __restrict__ Wf, unsigned* __restrict__ P8,
    int* __restrict__ tot, float* __restrict__ outz, int total8) {
  __shared__ unsigned sbuf[HW];   // 50 KB; hist uses all, count reuses prefix
  const int b = blockIdx.x;
  const int t = threadIdx.x;

  if (b < PREP_HIST) {
    // -------- u8-packed src histogram, single pass over all 50000 bins -----
    const int g = b >> 6;
    const int chunk = b & 63;
    const int E = A.E[g];
    const int per_chunk = (((E + NHCH - 1) / NHCH) + 3) & ~3;
    const int* __restrict__ keys = A.src[g];
    for (int i = t; i < HW; i += 256) sbuf[i] = 0;
    __syncthreads();
    const int e0 = chunk * per_chunk;
    const int e1 = min(e0 + per_chunk, E);
    const int nn = max(e1 - e0, 0);
    const int nv = nn >> 2;
    const int4* k4p = (const int4*)&keys[e0];
    for (int v = t; v < nv; v += 256) {
      int4 k = k4p[v];
      atomicAdd(&sbuf[(unsigned)k.x >> 2], 1u << (((unsigned)k.x & 3u) * 8));
      atomicAdd(&sbuf[(unsigned)k.y >> 2], 1u << (((unsigned)k.y & 3u) * 8));
      atomicAdd(&sbuf[(unsigned)k.z >> 2], 1u << (((unsigned)k.z & 3u) * 8));
      atomicAdd(&sbuf[(unsigned)k.w >> 2], 1u << (((unsigned)k.w & 3u) * 8));
    }
    for (int e = e0 + (nv << 2) + t; e < e1; e += 256) {
      unsigned k = (unsigned)keys[e];
      atomicAdd(&sbuf[k >> 2], 1u << ((k & 3u) * 8));
    }
    __syncthreads();
    unsigned* __restrict__ dstp = P8 + (size_t)b * HW;   // b == g*64+chunk
    for (int i = t; i < HW; i += 256) dstp[i] = sbuf[i];

  } else if (b < PREP_HIST + PREP_CNT) {
    // -------- coarse dst-bin count -----------------------------------------
    const int bb = b - PREP_HIST;
    const int g = bb / NPB;
    const int blk = bb % NPB;
    const int E = A.E[g];
    const int per_block = (((E + NPB - 1) / NPB) + 3) & ~3;
    const int* __restrict__ dst = A.dst[g];
    int* hcnt = (int*)sbuf;
    if (t < NC) hcnt[t] = 0;
    __syncthreads();
    const int e0 = blk * per_block;
    const int e1 = min(e0 + per_block, E);
    const int nn = max(e1 - e0, 0);
    const int nv = nn >> 2;
    const int4* d4 = (const int4*)&dst[e0];
    for (int v = t; v < nv; v += 256) {
      int4 d = d4[v];
      atomicAdd(&hcnt[(unsigned)d.x >> 9], 1);
      atomicAdd(&hcnt[(unsigned)d.y >> 9], 1);
      atomicAdd(&hcnt[(unsigned)d.z >> 9], 1);
      atomicAdd(&hcnt[(unsigned)d.w >> 9], 1);
    }
    for (int e = e0 + (nv << 2) + t; e < e1; e += 256)
      atomicAdd(&hcnt[(unsigned)dst[e] >> 9], 1);
    __syncthreads();
    if (t < NC && hcnt[t]) atomicAdd(&tot[g * NC + t], hcnt[t]);

  } else if (b < PREP_HIST + PREP_CNT + PREP_WF) {
    // -------- W -> MFMA B-fragment layout, PERMUTED columns ----------------
    // B-frag (c, lane n) holds logical W column (4n + c): MFMA C/D at lane n,
    // acc[c][r] is logical col 4n+c -> contiguous 8B epilogue store.
    int tid = (b - PREP_HIST - PREP_CNT) * 256 + t;   // < 3072 always
    int lane = tid & 63;
    int frag = (tid >> 6) & 15;
    int g = tid >> 10;
    int c = frag >> 2, kk = frag & 3;
    int n = lane & 15, quad = lane >> 4;
    const float* W = A.W[g];
    unsigned short v[8];
    #pragma unroll
    for (int j = 0; j < 8; ++j) {
      int k = 32 * kk + quad * 8 + j;
      v[j] = f2bf(W[k * 64 + 4 * n + c]);
    }
    uint4 u;
    u.x = (unsigned)v[0] | ((unsigned)v[1] << 16);
    u.y = (unsigned)v[2] | ((unsigned)v[3] << 16);
    u.z = (unsigned)v[4] | ((unsigned)v[5] << 16);
    u.w = (unsigned)v[6] | ((unsigned)v[7] << 16);
    ((uint4*)Wf)[tid] = u;

  } else {
    // -------- h fp32 -> bf16, and zero out (spmm accumulates atomically) ---
    const int cb = b - (PREP_HIST + PREP_CNT + PREP_WF);
    for (int i = cb * 256 + t; i < total8; i += PREP_CONV * 256) {
      const float4* hp = (const float4*)(h + (size_t)i * 8);
      float4 f0 = hp[0];
      float4 f1 = hp[1];
      uint4 u;
      u.x = (unsigned)f2bf(f0.x) | ((unsigned)f2bf(f0.y) << 16);
      u.y = (unsigned)f2bf(f0.z) | ((unsigned)f2bf(f0.w) << 16);
      u.z = (unsigned)f2bf(f1.x) | ((unsigned)f2bf(f1.y) << 16);
      u.w = (unsigned)f2bf(f1.z) | ((unsigned)f2bf(f1.w) << 16);
      ((uint4*)hb)[i] = u;
    }
    const int nout4 = total8;   // N*64 floats / 4 == N*128/8
    const float4 z = make_float4(0.f, 0.f, 0.f, 0.f);
    for (int i = cb * 256 + t; i < nout4; i += PREP_CONV * 256)
      ((float4*)outz)[i] = z;
  }
}

// ---------------- fused partition + MFMA GEMM -------------------------------
__global__ __launch_bounds__(512) void pg_kernel(
    GArgs A, const unsigned short* __restrict__ hb,
    const unsigned short* __restrict__ Wf, const unsigned* __restrict__ P8,
    unsigned short* __restrict__ x, const int* __restrict__ tot,
    int* __restrict__ cursor, unsigned* __restrict__ P2c, int N, int Emax) {
  __shared__ int sh[2 * NC + 128];
  const int b = blockIdx.x;
  const int t = threadIdx.x;

  if (b < PG_PART) {
    // ---------------- coarse partition (512 thr, zero-based cursor) --------
    int* lcnt = sh;
    int* lcur = sh + NC;
    int* sdp  = sh + 2 * NC;
    const int g = b / NPB;
    const int blk = b % NPB;
    const int E = A.E[g];
    const int per_block = (((E + NPB - 1) / NPB) + 3) & ~3;
    const int* __restrict__ src = A.src[g];
    const int* __restrict__ dst = A.dst[g];
    unsigned* __restrict__ P2g = P2c + (size_t)g * Emax;
    if (t < NC) lcnt[t] = 0;
    __syncthreads();
    const int e0 = blk * per_block;
    const int e1 = min(e0 + per_block, E);
    const int n = max(e1 - e0, 0);
    const int nv = n >> 2;
    const int4* d4 = (const int4*)&dst[e0];
    const int4* s4 = (const int4*)&src[e0];
    for (int v = t; v < nv; v += 512) {
      int4 d = d4[v];
      atomicAdd(&lcnt[(unsigned)d.x >> 9], 1);
      atomicAdd(&lcnt[(unsigned)d.y >> 9], 1);
      atomicAdd(&lcnt[(unsigned)d.z >> 9], 1);
      atomicAdd(&lcnt[(unsigned)d.w >> 9], 1);
    }
    for (int e = e0 + (nv << 2) + t; e < e1; e += 512)
      atomicAdd(&lcnt[(unsigned)dst[e] >> 9], 1);
    __syncthreads();
    // redundant exclusive scan of tot[g] (replaces scan_off kernel)
    if (t < 128) sdp[t] = (t < NC) ? tot[g * NC + t] : 0;
    __syncthreads();
    for (int o = 1; o < 128; o <<= 1) {
      int add = (t >= o && t < 128) ? sdp[t - o] : 0;
      __syncthreads();
      if (t < 128) sdp[t] += add;
      __syncthreads();
    }
    if (t < NC) {
      int c = lcnt[t];
      int excl = sdp[t] - tot[g * NC + t];
      lcur[t] = excl + (c ? atomicAdd(&cursor[g * NC + t], c) : 0);
    }
    __syncthreads();
    for (int v = t; v < nv; v += 512) {
      int4 d = d4[v];
      int4 s = s4[v];
      unsigned bk; int pos;
      bk = (unsigned)d.x >> 9; pos = atomicAdd(&lcur[bk], 1);
      P2g[pos] = (unsigned)s.x | (((unsigned)d.x & 511u) << 16);
      bk = (unsigned)d.y >> 9; pos = atomicAdd(&lcur[bk], 1);
      P2g[pos] = (unsigned)s.y | (((unsigned)d.y & 511u) << 16);
      bk = (unsigned)d.z >> 9; pos = atomicAdd(&lcur[bk], 1);
      P2g[pos] = (unsigned)s.z | (((unsigned)d.z & 511u) << 16);
      bk = (unsigned)d.w >> 9; pos = atomicAdd(&lcur[bk], 1);
      P2g[pos] = (unsigned)s.w | (((unsigned)d.w & 511u) << 16);
    }
    for (int e = e0 + (nv << 2) + t; e < e1; e += 512) {
      unsigned d = (unsigned)dst[e];
      unsigned bk = d >> 9;
      int pos = atomicAdd(&lcur[bk], 1);
      P2g[pos] = (unsigned)src[e] | ((d & 511u) << 16);
    }

  } else {
    // ---------------- MFMA GEMM (R14-verified) -----------------------------
    unsigned* ldegw = (unsigned*)sh;   // 64 u16-packed degrees
    const int gb = b - PG_PART;
    const int g = gb / PG_GEMM_PER;
    const int blk = gb % PG_GEMM_PER;
    const int row0 = blk * 128;
    unsigned short* __restrict__ xg = x + (size_t)g * N * NCOLS;

    if (t < 64) ldegw[t] = 0;
    __syncthreads();
    if (t < 256) {
      const unsigned* __restrict__ Pg = P8 + (size_t)g * NHCH * HW;
      const int widx = t >> 3;
      const int cg = t & 7;
      const int wcol = min((row0 >> 2) + widx, HW - 1);
      unsigned lo = 0, hi = 0;
      #pragma unroll
      for (int cc = 0; cc < 8; ++cc) {
        unsigned wv = Pg[(size_t)(cg * 8 + cc) * HW + wcol];
        lo += wv & 0x00FF00FFu;
        hi += (wv >> 8) & 0x00FF00FFu;
      }
      atomicAdd(&ldegw[2 * widx], lo);
      atomicAdd(&ldegw[2 * widx + 1], hi);
    }

    const int lane = t & 63;
    const int w = t >> 6;
    const int quad = lane >> 4;
    const int n = lane & 15;

    int arow = min(row0 + w * 16 + n, N - 1);
    const unsigned short* hrow = hb + (size_t)arow * KDIM + quad * 8;
    bf16x8 a0 = *(const bf16x8*)(hrow);
    bf16x8 a1 = *(const bf16x8*)(hrow + 32);
    bf16x8 a2 = *(const bf16x8*)(hrow + 64);
    bf16x8 a3 = *(const bf16x8*)(hrow + 96);

    const uint4* wfp = (const uint4*)Wf + (size_t)g * 1024 + lane;

    f32x4 acc[4];
    #pragma unroll
    for (int c = 0; c < 4; ++c) acc[c] = (f32x4)(0.f);

    __syncthreads();   // ldegw ready

    #pragma unroll
    for (int c = 0; c < 4; ++c) {
      union { uint4 u; bf16x8 v; } b0, b1, b2, b3;
      b0.u = wfp[(size_t)(c * 4 + 0) * 64];
      b1.u = wfp[(size_t)(c * 4 + 1) * 64];
      b2.u = wfp[(size_t)(c * 4 + 2) * 64];
      b3.u = wfp[(size_t)(c * 4 + 3) * 64];
      acc[c] = __builtin_amdgcn_mfma_f32_16x16x32_bf16(a0, b0.v, acc[c], 0, 0, 0);
      acc[c] = __builtin_amdgcn_mfma_f32_16x16x32_bf16(a1, b1.v, acc[c], 0, 0, 0);
      acc[c] = __builtin_amdgcn_mfma_f32_16x16x32_bf16(a2, b2.v, acc[c], 0, 0, 0);
      acc[c] = __builtin_amdgcn_mfma_f32_16x16x32_bf16(a3, b3.v, acc[c], 0, 0, 0);
    }

    const int rbase = row0 + w * 16 + quad * 4;
    #pragma unroll
    for (int r = 0; r < 4; ++r) {
      int row = rbase + r;
      if (row < N) {
        int lr = row - row0;
        float dg = (float)((ldegw[2 * (lr >> 2) + (lr & 1)] >> (((lr >> 1) & 1) * 16)) & 0xFFFFu);
        float s = rsqrtf(fmaxf(dg, 1.0f));
        uint2 o;
        o.x = (unsigned)f2bf(acc[0][r] * s) | ((unsigned)f2bf(acc[1][r] * s) << 16);
        o.y = (unsigned)f2bf(acc[2][r] * s) | ((unsigned)f2bf(acc[3][r] * s) << 16);
        *(uint2*)(xg + (size_t)row * NCOLS + 4 * n) = o;
      }
    }
  }
}

// ---------------- fine sort (redundant scan; otherwise unchanged) -----------
__global__ __launch_bounds__(512) void sort_fine_kernel(
    const unsigned* __restrict__ P2c, const int* __restrict__ tot,
    unsigned short* __restrict__ S, int* __restrict__ row_start,
    int N, int Emax) {
  __shared__ int cnt[COARSE];
  __shared__ int sd[COARSE];
  __shared__ int cur[COARSE];
  __shared__ int sds[128];
  __shared__ unsigned short outl[SFCAP];
  const int c = blockIdx.x;
  const int g = blockIdx.y;
  const unsigned* __restrict__ P2g = P2c + (size_t)g * Emax;
  const int t = threadIdx.x;

  // redundant exclusive scan of tot[g] -> base_e
  if (t < 128) sds[t] = (t < NC) ? tot[g * NC + t] : 0;
  __syncthreads();
  for (int o = 1; o < 128; o <<= 1) {
    int add = (t >= o && t < 128) ? sds[t - o] : 0;
    __syncthreads();
    if (t < 128) sds[t] += add;
    __syncthreads();
  }
  const int base_e = (c == 0) ? 0 : sds[c - 1];
  const int nloc = tot[g * NC + c];

  cnt[t] = 0;
  __syncthreads();
  for (int i = t; i < nloc; i += 512)
    atomicAdd(&cnt[(P2g[base_e + i] >> 16) & 511u], 1);
  __syncthreads();
  int v = cnt[t];
  sd[t] = v;
  __syncthreads();
  for (int o = 1; o < 512; o <<= 1) {
    int add = (t >= o) ? sd[t - o] : 0;
    __syncthreads();
    sd[t] += add;
    __syncthreads();
  }
  int excl = sd[t] - v;
  cur[t] = excl;
  int node = c * COARSE + t;
  if (node <= N) row_start[g * (N + 1) + node] = base_e + excl;
  __syncthreads();
  for (int i = t; i < nloc; i += 512) {
    unsigned p = P2g[base_e + i];
    int pos = atomicAdd(&cur[(p >> 16) & 511u], 1);
    if (pos < SFCAP) outl[pos] = (unsigned short)(p & 0xFFFFu);
  }
  __syncthreads();
  unsigned short* __restrict__ Sg = S + (size_t)g * Emax;
  for (int i = t; i < nloc; i += 512) Sg[base_e + i] = outl[i];
}

// ---------------- SpMM: per-(bucket,g), edge-balanced, LDS agg, atomic out --
__global__ __launch_bounds__(512) void spmm_all_kernel(
    GArgs A, const unsigned short* __restrict__ S,
    const int* __restrict__ row_start, const unsigned short* __restrict__ x,
    float* __restrict__ out, int N, int Emax) {
  __shared__ int rs[BUCKET + 1];
  __shared__ unsigned short srcs[FCAP];
  __shared__ float agg[BUCKET * NCOLS];   // 16 KB

  const int t = threadIdx.x;
  const int g = blockIdx.y;
  const int bk = blockIdx.x;
  const int dbase = bk * BUCKET;
  const int nd = min(BUCKET, N - dbase);
  const int grp = t >> 3;
  const int qe = (t & 7) * 8;

  const unsigned short* __restrict__ Sg = S + (size_t)g * Emax;
  const int* __restrict__ rsg = row_start + (size_t)g * (N + 1);
  const unsigned short* __restrict__ xg = x + (size_t)g * N * NCOLS;

  if (t <= BUCKET) rs[t] = rsg[min(dbase + t, N)];
  for (int i = t; i < BUCKET * NCOLS; i += 512) agg[i] = 0.f;
  __syncthreads();
  const int e0 = rs[0];
  const int ne = min(rs[BUCKET] - e0, FCAP);
  for (int i = t; i < ne; i += 512) srcs[i] = Sg[e0 + i];
  __syncthreads();

  // edge-balanced: group handles local edges [grp*W, min(grp*W+W, ne))
  const int W = (ne + BUCKET - 1) >> 6;
  int i = grp * W;
  const int w1 = min(i + W, ne);
  if (i < w1) {
    // binary search: node = max n with rs[n]-e0 <= i  (rs[0]-e0=0<=i<ne)
    int lo = 0, hi = BUCKET;
    while (hi - lo > 1) {
      int mid = (lo + hi) >> 1;
      if (rs[mid] - e0 <= i) lo = mid; else hi = mid;
    }
    int node = lo;
    int nend = min(rs[node + 1] - e0, ne);
    float a0 = 0.f, a1 = 0.f, a2 = 0.f, a3 = 0.f;
    float a4 = 0.f, a5 = 0.f, a6 = 0.f, a7 = 0.f;
    for (; i < w1; ++i) {
      if (i >= nend) {
        float* ap = &agg[node * NCOLS + qe];
        atomicAdd(&ap[0], a0); atomicAdd(&ap[1], a1);
        atomicAdd(&ap[2], a2); atomicAdd(&ap[3], a3);
        atomicAdd(&ap[4], a4); atomicAdd(&ap[5], a5);
        atomicAdd(&ap[6], a6); atomicAdd(&ap[7], a7);
        a0 = a1 = a2 = a3 = a4 = a5 = a6 = a7 = 0.f;
        do { ++node; nend = min(rs[node + 1] - e0, ne); } while (nend <= i);
      }
      unsigned sv = srcs[i];
      const uint4 u = *(const uint4*)&xg[(size_t)sv * NCOLS + qe];
      a0 += bflo(u.x); a1 += bfhi(u.x);
      a2 += bflo(u.y); a3 += bfhi(u.y);
      a4 += bflo(u.z); a5 += bfhi(u.z);
      a6 += bflo(u.w); a7 += bfhi(u.w);
    }
    float* ap = &agg[node * NCOLS + qe];
    atomicAdd(&ap[0], a0); atomicAdd(&ap[1], a1);
    atomicAdd(&ap[2], a2); atomicAdd(&ap[3], a3);
    atomicAdd(&ap[4], a4); atomicAdd(&ap[5], a5);
    atomicAdd(&ap[6], a6); atomicAdd(&ap[7], a7);
  }
  __syncthreads();

  // epilogue: scale + bias + relu + /3, atomic accumulate across graphs
  const float* __restrict__ bg = A.b[g];
  for (int idx = t; idx < nd * NCOLS; idx += 512) {
    int node = idx >> 6;
    int col = idx & 63;
    int deg = rs[node + 1] - rs[node];
    float sc2 = rsqrtf(fmaxf((float)deg, 1.0f));
    float v = fmaxf(fmaf(agg[idx], sc2, bg[col]), 0.f) * (1.0f / 3.0f);
    atomicAdd(&out[(size_t)(dbase + node) * NCOLS + col], v);
  }
}

extern "C" void kernel_launch(void* const* d_in, const int* in_sizes, int n_in,
                              void* d_out, int out_size, void* d_ws, size_t ws_size,
                              hipStream_t stream) {
  const float* h = (const float*)d_in[0];
  const int N = in_sizes[0] / KDIM;   // 50000
  float* out = (float*)d_out;

  GArgs A;
  int Emax = 0;
  for (int g = 0; g < 3; ++g) {
    A.src[g] = (const int*)  d_in[1 + g * 4];
    A.dst[g] = (const int*)  d_in[2 + g * 4];
    A.W[g]   = (const float*)d_in[3 + g * 4];
    A.b[g]   = (const float*)d_in[4 + g * 4];
    A.E[g]   = in_sizes[1 + g * 4];
    if (A.E[g] > Emax) Emax = A.E[g];
  }

  // ws: x 19.2 | hb 12.8 | P2c 19.2 | P8 9.6 | S 9.6 | Wf 48K | rs 0.6 MB
  char* w = (char*)d_ws;
  unsigned short* x = (unsigned short*)w;
  char* w2 = w + (size_t)3 * N * NCOLS * sizeof(unsigned short);
  unsigned short* hb = (unsigned short*)w2;
  char* w3 = w2 + (size_t)N * KDIM * sizeof(unsigned short);
  unsigned* P2c = (unsigned*)w3;
  char* w4 = w3 + (size_t)3 * Emax * sizeof(unsigned);
  unsigned* P8 = (unsigned*)w4;
  char* w5 = w4 + (size_t)3 * NHCH * HW * sizeof(unsigned);
  unsigned short* S = (unsigned short*)w5;
  char* w6 = w5 + (size_t)3 * Emax * sizeof(unsigned short);
  unsigned short* Wf = (unsigned short*)w6;            // 3*16*64*8 u16 = 48 KB
  char* w7 = w6 + (size_t)3 * 16 * 64 * 8 * sizeof(unsigned short);
  int* row_start = (int*)w7;
  char* w8 = w7 + (size_t)3 * (N + 1) * sizeof(int);
  int* tot    = (int*)w8;
  int* cursor = tot + 3 * NC;

  hipMemsetAsync(tot, 0, 2 * 3 * NC * sizeof(int), stream);
  const int total8 = N * KDIM / 8;
  prep_kernel<<<PREP_GRID, 256, 0, stream>>>(A, h, hb, Wf, P8, tot, out, total8);
  pg_kernel<<<PG_GRID, 512, 0, stream>>>(A, hb, Wf, P8, x, tot, cursor, P2c, N, Emax);
  sort_fine_kernel<<<dim3(NC, 3), 512, 0, stream>>>(P2c, tot, S, row_start, N, Emax);
  spmm_all_kernel<<<dim3(NBUCK, 3), 512, 0, stream>>>(A, S, row_start, x, out, N, Emax);
}